// Round 5
// baseline (632.263 us; speedup 1.0000x reference)
//
#include <hip/hip_runtime.h>

#define BB 512
#define TT 1024
#define II 50
#define HH 32
#define CH 16            // steps per chunk (barrier cadence; = MFMA M)
#define NCH (TT / CH)    // 64 chunks
#define RSLOT 32         // ring slots = 2 chunks (double buffer)

typedef float v2f __attribute__((ext_vector_type(2)));
typedef float v4f __attribute__((ext_vector_type(4)));
typedef short v8s __attribute__((ext_vector_type(8)));   // 8 bf16 (4 VGPRs)

__device__ __forceinline__ float fast_rcp(float x) { return __builtin_amdgcn_rcpf(x); }
__device__ __forceinline__ float sigm(float x) { return fast_rcp(1.f + __expf(-x)); }
__device__ __forceinline__ float tanh_(float x) {
    return 1.f - 2.f * fast_rcp(1.f + __expf(2.f * x));   // saturates correctly
}
__device__ __forceinline__ short bf16rne(float f) {      // fp32 -> bf16 RNE
    unsigned u = __float_as_uint(f);
    u += 0x7FFF + ((u >> 16) & 1);
    return (short)(u >> 16);
}

// Cross-half (lane ^ 32) sum via v_permlane32_swap: pure-VALU (~2cy), stays
// off the LDS pipe. The returned pair {r0,r1} contains {own,partner} per
// lane in either hardware convention, so r0+r1 is convention-independent.
#if __has_builtin(__builtin_amdgcn_permlane32_swap)
typedef unsigned v2u __attribute__((ext_vector_type(2)));
__device__ __forceinline__ float xhalf_sum(float p) {
    v2u r = __builtin_amdgcn_permlane32_swap(__float_as_uint(p),
                                             __float_as_uint(p), false, false);
    return __uint_as_float(r.x) + __uint_as_float(r.y);
}
#else
__device__ __forceinline__ float xhalf_sum(float p) {
    return p + __shfl_xor(p, 32, 64);
}
#endif

// d_out is poisoned before every launch: init every element to the combined
// FC bias b_comb = fc3_w @ fc1_b + fc3_b (fc1->fc3 is affine-affine; dropout
// is identity in eval). The scan kernel atomicAdds partial dots on top.
__global__ void init_out_kernel(float* __restrict__ out,
                                const float* __restrict__ fc1_b,
                                const float* __restrict__ fc3_w,
                                const float* __restrict__ fc3_b,
                                int n) {
    int idx = blockIdx.x * blockDim.x + threadIdx.x;
    float b = fc3_b[0];
    #pragma unroll
    for (int k = 0; k < 64; ++k) b += fc3_w[k] * fc1_b[k];
    if (idx < n) out[idx] = b;
}

// One workgroup (192 threads = 3 waves) per BATCH.
//   wave 0 = CONSUMER fwd, wave 1 = CONSUMER rev. Within a consumer wave,
//            lanes (k, kh=lane>>5): unit k, K-half kh. Each lane computes a
//            HALF-dot (K=16 -> 32 pk_fma/wave instead of 64), combined with
//            one v_permlane32_swap per gate (VALU, not LDS). Activations and
//            c/h state are duplicated across kh halves (same wave-wide
//            instructions, zero extra issue).
//   wave 2 = PRODUCER: ih projection for BOTH dirs via bf16 MFMA
//            (32 MFMA / 16-step chunk), plus deferred-FC flush + atomicAdd.
// Ring layout (per step-slot, 256 floats): col = d*128 + cidx(gate);
//   cidx: i_k->2k, f_k->2k+1, g_k->64+2k, o_k->64+2k+1, so a consumer lane
//   reads two b64s: {zi,zf} at d*128+2k and {zg,zo} at d*128+64+2k.
// Bias is seeded in the kh=0 half-dot accumulator (added exactly once).
// MFMA layouts (guide-verified m89/m118/m120):
//   A (16x32): m=lane&15, k=(lane>>4)*8+j     (8 bf16/lane)
//   B (32x16): n=lane&15, k=(lane>>4)*8+j
//   D (16x16): m=(lane>>4)*4+reg, n=lane&15   (4 fp32/lane)
// CRITICAL (prior-session lesson): empty asm memory clobber at the end of
// each consumer step pins the hst store->load order across unrolled steps.
__global__ void __launch_bounds__(192, 1) lstm_pc_kernel(
    const float* __restrict__ x,
    const float* __restrict__ w_ih_f, const float* __restrict__ w_hh_f,
    const float* __restrict__ b_ih_f, const float* __restrict__ b_hh_f,
    const float* __restrict__ w_ih_r, const float* __restrict__ w_hh_r,
    const float* __restrict__ b_ih_r, const float* __restrict__ b_hh_r,
    const float* __restrict__ fc1_w, const float* __restrict__ fc3_w,
    float* __restrict__ out)
{
    __shared__ float ringF[RSLOT * 256];        // 32 KB: per-step gate projections
    __shared__ float hbuf[2][HH][65];           // 16.6 KB: deferred FC partials
    __shared__ __align__(16) float hst[64];     // 256 B: h(t-1) stage, both dirs

    const int tid  = threadIdx.x;
    const int lane = tid & 63;
    const int wave = tid >> 6;            // 0 fwd consumer, 1 rev consumer, 2 producer
    const int b    = blockIdx.x;
    float* outb = out + (size_t)b * TT;

    if (wave == 2) {
        // ================= PRODUCER (MFMA ih projection, both dirs) =========
        const float* xb = x + (size_t)b * TT * II;
        const int nl = lane & 15;         // A: m / B: n / D: n
        const int q  = lane >> 4;         // quad 0..3
        const float* wih[2] = {w_ih_f, w_ih_r};

        // B fragments (persistent): Bf[d][nt][kf], n = nt*16+nl, k = kf*32+q*8+j
        v8s Bf[2][8][2];
        #pragma unroll
        for (int d = 0; d < 2; ++d)
            #pragma unroll
            for (int nt = 0; nt < 8; ++nt) {
                const int n = nt * 16 + nl;
                #pragma unroll
                for (int kf = 0; kf < 2; ++kf)
                    #pragma unroll
                    for (int j = 0; j < 8; ++j) {
                        const int k = kf * 32 + q * 8 + j;
                        Bf[d][nt][kf][j] = (k < II) ? bf16rne(wih[d][n * II + k])
                                                    : (short)0;
                    }
            }

        // gate g -> interleaved ring column
        auto cidx = [](int g) -> int {
            return (g < 32) ? 2 * g
                 : (g < 64) ? 2 * (g - 32) + 1
                 : (g < 96) ? 64 + 2 * (g - 64)
                            : 64 + 2 * (g - 96) + 1;
        };

        // produce chunk c for both dirs: fills ring slots c*CH .. c*CH+15
        auto produce_chunk = [&](int c) {
            #pragma unroll
            for (int d = 0; d < 2; ++d) {
                const int S = c * CH + nl;             // this lane's A-row step
                const int t = d ? (TT - 1 - S) : S;
                const float* xr = xb + (size_t)t * II;
                v8s A0, A1;
                #pragma unroll
                for (int j = 0; j < 8; ++j) A0[j] = bf16rne(xr[q * 8 + j]);
                #pragma unroll
                for (int j = 0; j < 8; ++j) {
                    const int k = 32 + q * 8 + j;
                    A1[j] = (k < II) ? bf16rne(xr[k]) : (short)0;
                }
                #pragma unroll
                for (int nt = 0; nt < 8; ++nt) {
                    v4f acc = {0.f, 0.f, 0.f, 0.f};
                    acc = __builtin_amdgcn_mfma_f32_16x16x32_bf16(A0, Bf[d][nt][0], acc, 0, 0, 0);
                    acc = __builtin_amdgcn_mfma_f32_16x16x32_bf16(A1, Bf[d][nt][1], acc, 0, 0, 0);
                    const int col = d * 128 + cidx(nt * 16 + nl);
                    #pragma unroll
                    for (int r = 0; r < 4; ++r) {
                        const int slot = (c * CH + q * 4 + r) & (RSLOT - 1);
                        ringF[slot * 256 + col] = acc[r];
                    }
                }
            }
        };
        // flush chunk m: 16 outputs per dir; lanes 0..31 (d = lane>>4)
        auto flush = [&](int m) {
            if (lane < 32) {
                const int d   = lane >> 4;
                const int idx = lane & 15;
                const int ti  = m * CH + idx;
                const int col = ti & 63;
                float d0 = 0.f, d1 = 0.f, d2 = 0.f, d3 = 0.f;
                #pragma unroll
                for (int k = 0; k < HH; k += 4) {
                    d0 += hbuf[d][k    ][col];
                    d1 += hbuf[d][k + 1][col];
                    d2 += hbuf[d][k + 2][col];
                    d3 += hbuf[d][k + 3][col];
                }
                const int t = d ? (TT - 1 - ti) : ti;
                atomicAdd(&outb[t], (d0 + d1) + (d2 + d3));
            }
        };

        produce_chunk(0);
        __syncthreads();
        for (int n = 0; n < NCH; ++n) {
            if (n + 1 < NCH) produce_chunk(n + 1);
            if (n >= 1) flush(n - 1);
            __syncthreads();
        }
        flush(NCH - 1);
    } else {
        // ================= CONSUMER (fp32 recurrence, dir = wave) ==========
        const int d  = wave;              // 0 fwd, 1 rev
        const int k  = lane & 31;         // hidden unit
        const int kh = lane >> 5;         // K-half: 0 -> h[0..15], 1 -> h[16..31]
        const float* w_hh = d ? w_hh_r : w_hh_f;
        const float* bi   = d ? b_ih_r : b_ih_f;
        const float* bh   = d ? b_hh_r : b_hh_f;

        // K-packed weight pairs for this lane's K-half of all 4 gate rows:
        // wp[D][j] = {w_hh[D*32+k][16*kh+2j], w_hh[D*32+k][16*kh+2j+1]}
        v2f wp[4][8];
        float bseed[4];
        #pragma unroll
        for (int D = 0; D < 4; ++D) {
            const int row = D * 32 + k;
            #pragma unroll
            for (int j = 0; j < 8; ++j) {
                wp[D][j].x = w_hh[row * HH + 16 * kh + 2 * j];
                wp[D][j].y = w_hh[row * HH + 16 * kh + 2 * j + 1];
            }
            bseed[D] = kh ? 0.f : (bi[row] + bh[row]);   // bias added once
        }

        // fused FC weight for hidden unit j = d*32 + k
        float wc = 0.f;
        {
            const int j = d * HH + k;
            #pragma unroll
            for (int n = 0; n < 64; ++n) wc += fc3_w[n] * fc1_w[n * 64 + j];
        }

        hst[d * 32 + k] = 0.f;            // h(-1)=0 (kh halves write same value)
        float c = 0.f;

        __syncthreads();                  // matches producer's prologue barrier

        for (int n = 0; n < NCH; ++n) {
            const int slot0 = (n & 1) * CH;
            const int col0  = (n & 3) * CH;
            #pragma unroll
            for (int u = 0; u < CH; ++u) {
                // x-projection pairs (off-chain: issued at step top, used late)
                const float* rp = &ringF[(slot0 + u) * 256 + d * 128 + 2 * k];
                const v2f xz1 = *(const v2f*)rp;          // {px_i, px_f}
                const v2f xz2 = *(const v2f*)(rp + 64);   // {px_g, px_o}

                // h(t-1) broadcast, this lane's K-half only: 4x b128
                float4 h4[4];
                #pragma unroll
                for (int j = 0; j < 4; ++j)
                    h4[j] = *(const float4*)&hst[d * 32 + kh * 16 + 4 * j];

                v2f acc[4];
                #pragma unroll
                for (int D = 0; D < 4; ++D) acc[D] = (v2f){bseed[D], 0.f};
                #pragma unroll
                for (int j = 0; j < 4; ++j) {
                    v2f p0 = {h4[j].x, h4[j].y};          // adjacent regs, free
                    v2f p1 = {h4[j].z, h4[j].w};
                    #pragma unroll
                    for (int D = 0; D < 4; ++D) {
                        acc[D] = __builtin_elementwise_fma(p0, wp[D][2 * j    ], acc[D]);
                        acc[D] = __builtin_elementwise_fma(p1, wp[D][2 * j + 1], acc[D]);
                    }
                }
                // half-dot -> full dot: horizontal add, then lane^32 combine
                const float zi = xhalf_sum(acc[0].x + acc[0].y) + xz1.x;
                const float zf = xhalf_sum(acc[1].x + acc[1].y) + xz1.y;
                const float zg = xhalf_sum(acc[2].x + acc[2].y) + xz2.x;
                const float zo = xhalf_sum(acc[3].x + acc[3].y) + xz2.y;

                const float gi = sigm(zi);
                const float gf = sigm(zf);
                const float gg = tanh_(zg);
                const float go = sigm(zo);

                c = fmaf(gf, c, gi * gg);
                const float h = go * tanh_(c);

                hst[d * 32 + k] = h;                  // kh halves write same value
                hbuf[d][k][col0 + u] = h * wc;        // deferred FC (dup write ok)
                // ordering fence: store(u) may not sink, loads(u+1) may not
                // hoist. Zero instructions emitted.
                asm volatile("" ::: "memory");
            }
            __syncthreads();
        }
    }
}

extern "C" void kernel_launch(void* const* d_in, const int* in_sizes, int n_in,
                              void* d_out, int out_size, void* d_ws, size_t ws_size,
                              hipStream_t stream) {
    const float* x      = (const float*)d_in[0];
    const float* w_ih_f = (const float*)d_in[1];
    const float* w_hh_f = (const float*)d_in[2];
    const float* b_ih_f = (const float*)d_in[3];
    const float* b_hh_f = (const float*)d_in[4];
    const float* w_ih_r = (const float*)d_in[5];
    const float* w_hh_r = (const float*)d_in[6];
    const float* b_ih_r = (const float*)d_in[7];
    const float* b_hh_r = (const float*)d_in[8];
    const float* fc1_w  = (const float*)d_in[9];
    const float* fc1_b  = (const float*)d_in[10];
    const float* fc3_w  = (const float*)d_in[11];
    const float* fc3_b  = (const float*)d_in[12];
    float* out = (float*)d_out;

    const int n = BB * TT;
    init_out_kernel<<<(n + 255) / 256, 256, 0, stream>>>(out, fc1_b, fc3_w, fc3_b, n);

    // 512 workgroups = batches; 3 waves each (fwd consumer, rev consumer, producer).
    lstm_pc_kernel<<<BB, 192, 0, stream>>>(
        x, w_ih_f, w_hh_f, b_ih_f, b_hh_f,
        w_ih_r, w_hh_r, b_ih_r, b_hh_r,
        fc1_w, fc3_w, out);
}

// Round 6
// 548.662 us; speedup vs baseline: 1.1524x; 1.1524x over previous
//
#include <hip/hip_runtime.h>

#define BB 512
#define TT 1024
#define II 50
#define HH 32
#define CH 16            // steps per chunk (barrier cadence; = MFMA M)
#define NCH (TT / CH)    // 64 chunks
#define RSLOT 32         // ring slots = 2 chunks (double buffer)

typedef float v2f __attribute__((ext_vector_type(2)));
typedef float v4f __attribute__((ext_vector_type(4)));
typedef short v8s __attribute__((ext_vector_type(8)));   // 8 bf16 (4 VGPRs)

__device__ __forceinline__ float fast_rcp(float x) { return __builtin_amdgcn_rcpf(x); }
__device__ __forceinline__ float sigm(float x) { return fast_rcp(1.f + __expf(-x)); }
__device__ __forceinline__ float tanh_(float x) {
    return 1.f - 2.f * fast_rcp(1.f + __expf(2.f * x));   // saturates correctly
}
__device__ __forceinline__ short bf16rne(float f) {      // fp32 -> bf16 RNE
    unsigned u = __float_as_uint(f);
    u += 0x7FFF + ((u >> 16) & 1);
    return (short)(u >> 16);
}

// Cross-half (lane ^ 32) sum via v_permlane32_swap: pure-VALU, stays off the
// LDS pipe. The returned pair {r0,r1} contains {own,partner} per lane in
// either hardware convention, so r0+r1 is convention-independent.
#if __has_builtin(__builtin_amdgcn_permlane32_swap)
typedef unsigned v2u __attribute__((ext_vector_type(2)));
__device__ __forceinline__ float xhalf_sum(float p) {
    v2u r = __builtin_amdgcn_permlane32_swap(__float_as_uint(p),
                                             __float_as_uint(p), false, false);
    return __uint_as_float(r.x) + __uint_as_float(r.y);
}
#else
__device__ __forceinline__ float xhalf_sum(float p) {
    return p + __shfl_xor(p, 32, 64);
}
#endif

// d_out is poisoned before every launch: init every element to the combined
// FC bias b_comb = fc3_w @ fc1_b + fc3_b (fc1->fc3 is affine-affine; dropout
// is identity in eval). The scan kernel atomicAdds partial dots on top.
__global__ void init_out_kernel(float* __restrict__ out,
                                const float* __restrict__ fc1_b,
                                const float* __restrict__ fc3_w,
                                const float* __restrict__ fc3_b,
                                int n) {
    int idx = blockIdx.x * blockDim.x + threadIdx.x;
    float b = fc3_b[0];
    #pragma unroll
    for (int k = 0; k < 64; ++k) b += fc3_w[k] * fc1_b[k];
    if (idx < n) out[idx] = b;
}

// One workgroup (384 threads = 6 waves) per PAIR of batches.
// R5 lesson (counters): a 192-thread/48.5KB-LDS block got only ONE block/CU
// resident (Occupancy 8.77% ~= 3 waves/CU) -> 512 blocks ran as 2 sequential
// rounds (529 ~= 2 x 264.5 us). The per-step restructure itself HELPED
// (757 -> ~620 cy/step). Fix: 2 batches per block, 256 blocks = exactly one
// per CU BY CONSTRUCTION (99KB LDS forbids 2/CU), one round covers all work.
//   waves 0,1,2 = sub-batch 0: {fwd consumer, rev consumer, producer}
//   waves 3,4,5 = sub-batch 1: {fwd consumer, rev consumer, producer}
// Consumer wave (one direction): lanes (k=lane&31, kh=lane>>5): unit k,
//   K-half kh. Each lane computes a HALF-dot (K=16 -> 32 pk_fma/wave),
//   combined with one v_permlane32_swap per gate (VALU, not LDS).
//   Activations and c/h state are duplicated across kh halves.
// Producer wave: ih projection for BOTH dirs of its sub-batch via bf16 MFMA
//   (32 MFMA / 16-step chunk), plus deferred-FC flush + atomicAdd.
// Ring layout (per step-slot, 256 floats): col = d*128 + cidx(gate);
//   cidx: i_k->2k, f_k->2k+1, g_k->64+2k, o_k->64+2k+1, so a consumer lane
//   reads two b64s: {zi,zf} at d*128+2k and {zg,zo} at d*128+64+2k.
// Bias is seeded in the kh=0 half-dot accumulator (added exactly once).
// MFMA layouts (guide-verified m89/m118/m120):
//   A (16x32): m=lane&15, k=(lane>>4)*8+j     (8 bf16/lane)
//   B (32x16): n=lane&15, k=(lane>>4)*8+j
//   D (16x16): m=(lane>>4)*4+reg, n=lane&15   (4 fp32/lane)
// CRITICAL (prior-session lesson): empty asm memory clobber at the end of
// each consumer step pins the hst store->load order across unrolled steps.
// NOTE: __syncthreads() couples both sub-batches' chunk cadence; producers
// have ~5x slack per chunk so the coupling cost is small.
__global__ void __launch_bounds__(384, 1) lstm_pc_kernel(
    const float* __restrict__ x,
    const float* __restrict__ w_ih_f, const float* __restrict__ w_hh_f,
    const float* __restrict__ b_ih_f, const float* __restrict__ b_hh_f,
    const float* __restrict__ w_ih_r, const float* __restrict__ w_hh_r,
    const float* __restrict__ b_ih_r, const float* __restrict__ b_hh_r,
    const float* __restrict__ fc1_w, const float* __restrict__ fc3_w,
    float* __restrict__ out)
{
    __shared__ float ringF[2][RSLOT * 256];     // 64 KB: per-step gate projections
    __shared__ float hbuf[2][2][HH][65];        // 33.3 KB: deferred FC partials
    __shared__ __align__(16) float hst[2][64];  // 512 B: h(t-1) stage, both dirs

    const int tid  = threadIdx.x;
    const int lane = tid & 63;
    const int wave = tid >> 6;            // 0..5
    const int sb   = wave / 3;            // sub-batch within block (0/1)
    const int role = wave - 3 * sb;       // 0 fwd cons, 1 rev cons, 2 producer
    const int b    = blockIdx.x * 2 + sb;
    float* outb = out + (size_t)b * TT;
    float* ring = ringF[sb];

    if (role == 2) {
        // ================= PRODUCER (MFMA ih projection, both dirs) =========
        const float* xb = x + (size_t)b * TT * II;
        const int nl = lane & 15;         // A: m / B: n / D: n
        const int q  = lane >> 4;         // quad 0..3
        const float* wih[2] = {w_ih_f, w_ih_r};

        // B fragments (persistent): Bf[d][nt][kf], n = nt*16+nl, k = kf*32+q*8+j
        v8s Bf[2][8][2];
        #pragma unroll
        for (int d = 0; d < 2; ++d)
            #pragma unroll
            for (int nt = 0; nt < 8; ++nt) {
                const int n = nt * 16 + nl;
                #pragma unroll
                for (int kf = 0; kf < 2; ++kf)
                    #pragma unroll
                    for (int j = 0; j < 8; ++j) {
                        const int k = kf * 32 + q * 8 + j;
                        Bf[d][nt][kf][j] = (k < II) ? bf16rne(wih[d][n * II + k])
                                                    : (short)0;
                    }
            }

        // gate g -> interleaved ring column
        auto cidx = [](int g) -> int {
            return (g < 32) ? 2 * g
                 : (g < 64) ? 2 * (g - 32) + 1
                 : (g < 96) ? 64 + 2 * (g - 64)
                            : 64 + 2 * (g - 96) + 1;
        };

        // produce chunk c for both dirs: fills ring slots c*CH .. c*CH+15
        auto produce_chunk = [&](int c) {
            #pragma unroll
            for (int d = 0; d < 2; ++d) {
                const int S = c * CH + nl;             // this lane's A-row step
                const int t = d ? (TT - 1 - S) : S;
                const float* xr = xb + (size_t)t * II;
                v8s A0, A1;
                #pragma unroll
                for (int j = 0; j < 8; ++j) A0[j] = bf16rne(xr[q * 8 + j]);
                #pragma unroll
                for (int j = 0; j < 8; ++j) {
                    const int k = 32 + q * 8 + j;
                    A1[j] = (k < II) ? bf16rne(xr[k]) : (short)0;
                }
                #pragma unroll
                for (int nt = 0; nt < 8; ++nt) {
                    v4f acc = {0.f, 0.f, 0.f, 0.f};
                    acc = __builtin_amdgcn_mfma_f32_16x16x32_bf16(A0, Bf[d][nt][0], acc, 0, 0, 0);
                    acc = __builtin_amdgcn_mfma_f32_16x16x32_bf16(A1, Bf[d][nt][1], acc, 0, 0, 0);
                    const int col = d * 128 + cidx(nt * 16 + nl);
                    #pragma unroll
                    for (int r = 0; r < 4; ++r) {
                        const int slot = (c * CH + q * 4 + r) & (RSLOT - 1);
                        ring[slot * 256 + col] = acc[r];
                    }
                }
            }
        };
        // flush chunk m: 16 outputs per dir; lanes 0..31 (d = lane>>4)
        auto flush = [&](int m) {
            if (lane < 32) {
                const int d   = lane >> 4;
                const int idx = lane & 15;
                const int ti  = m * CH + idx;
                const int col = ti & 63;
                float d0 = 0.f, d1 = 0.f, d2 = 0.f, d3 = 0.f;
                #pragma unroll
                for (int k = 0; k < HH; k += 4) {
                    d0 += hbuf[sb][d][k    ][col];
                    d1 += hbuf[sb][d][k + 1][col];
                    d2 += hbuf[sb][d][k + 2][col];
                    d3 += hbuf[sb][d][k + 3][col];
                }
                const int t = d ? (TT - 1 - ti) : ti;
                atomicAdd(&outb[t], (d0 + d1) + (d2 + d3));
            }
        };

        produce_chunk(0);
        __syncthreads();
        for (int n = 0; n < NCH; ++n) {
            if (n + 1 < NCH) produce_chunk(n + 1);
            if (n >= 1) flush(n - 1);
            __syncthreads();
        }
        flush(NCH - 1);
    } else {
        // ================= CONSUMER (fp32 recurrence, dir = role) ==========
        const int d  = role;              // 0 fwd, 1 rev
        const int k  = lane & 31;         // hidden unit
        const int kh = lane >> 5;         // K-half: 0 -> h[0..15], 1 -> h[16..31]
        const float* w_hh = d ? w_hh_r : w_hh_f;
        const float* bi   = d ? b_ih_r : b_ih_f;
        const float* bh   = d ? b_hh_r : b_hh_f;

        // K-packed weight pairs for this lane's K-half of all 4 gate rows:
        // wp[D][j] = {w_hh[D*32+k][16*kh+2j], w_hh[D*32+k][16*kh+2j+1]}
        v2f wp[4][8];
        float bseed[4];
        #pragma unroll
        for (int D = 0; D < 4; ++D) {
            const int row = D * 32 + k;
            #pragma unroll
            for (int j = 0; j < 8; ++j) {
                wp[D][j].x = w_hh[row * HH + 16 * kh + 2 * j];
                wp[D][j].y = w_hh[row * HH + 16 * kh + 2 * j + 1];
            }
            bseed[D] = kh ? 0.f : (bi[row] + bh[row]);   // bias added once
        }

        // fused FC weight for hidden unit j = d*32 + k
        float wc = 0.f;
        {
            const int j = d * HH + k;
            #pragma unroll
            for (int n = 0; n < 64; ++n) wc += fc3_w[n] * fc1_w[n * 64 + j];
        }

        hst[sb][d * 32 + k] = 0.f;        // h(-1)=0 (kh halves write same value)
        float c = 0.f;

        __syncthreads();                  // matches producer's prologue barrier

        for (int n = 0; n < NCH; ++n) {
            const int slot0 = (n & 1) * CH;
            const int col0  = (n & 3) * CH;
            #pragma unroll
            for (int u = 0; u < CH; ++u) {
                // x-projection pairs (off-chain: issued at step top, used late)
                const float* rp = &ring[(slot0 + u) * 256 + d * 128 + 2 * k];
                const v2f xz1 = *(const v2f*)rp;          // {px_i, px_f}
                const v2f xz2 = *(const v2f*)(rp + 64);   // {px_g, px_o}

                // h(t-1) broadcast, this lane's K-half only: 4x b128
                float4 h4[4];
                #pragma unroll
                for (int j = 0; j < 4; ++j)
                    h4[j] = *(const float4*)&hst[sb][d * 32 + kh * 16 + 4 * j];

                v2f acc[4];
                #pragma unroll
                for (int D = 0; D < 4; ++D) acc[D] = (v2f){bseed[D], 0.f};
                #pragma unroll
                for (int j = 0; j < 4; ++j) {
                    v2f p0 = {h4[j].x, h4[j].y};          // adjacent regs, free
                    v2f p1 = {h4[j].z, h4[j].w};
                    #pragma unroll
                    for (int D = 0; D < 4; ++D) {
                        acc[D] = __builtin_elementwise_fma(p0, wp[D][2 * j    ], acc[D]);
                        acc[D] = __builtin_elementwise_fma(p1, wp[D][2 * j + 1], acc[D]);
                    }
                }
                // half-dot -> full dot: horizontal add, then lane^32 combine
                const float zi = xhalf_sum(acc[0].x + acc[0].y) + xz1.x;
                const float zf = xhalf_sum(acc[1].x + acc[1].y) + xz1.y;
                const float zg = xhalf_sum(acc[2].x + acc[2].y) + xz2.x;
                const float zo = xhalf_sum(acc[3].x + acc[3].y) + xz2.y;

                const float gi = sigm(zi);
                const float gf = sigm(zf);
                const float gg = tanh_(zg);
                const float go = sigm(zo);

                c = fmaf(gf, c, gi * gg);
                const float h = go * tanh_(c);

                hst[sb][d * 32 + k] = h;              // kh halves write same value
                hbuf[sb][d][k][col0 + u] = h * wc;    // deferred FC (dup write ok)
                // ordering fence: store(u) may not sink, loads(u+1) may not
                // hoist. Zero instructions emitted.
                asm volatile("" ::: "memory");
            }
            __syncthreads();
        }
    }
}

extern "C" void kernel_launch(void* const* d_in, const int* in_sizes, int n_in,
                              void* d_out, int out_size, void* d_ws, size_t ws_size,
                              hipStream_t stream) {
    const float* x      = (const float*)d_in[0];
    const float* w_ih_f = (const float*)d_in[1];
    const float* w_hh_f = (const float*)d_in[2];
    const float* b_ih_f = (const float*)d_in[3];
    const float* b_hh_f = (const float*)d_in[4];
    const float* w_ih_r = (const float*)d_in[5];
    const float* w_hh_r = (const float*)d_in[6];
    const float* b_ih_r = (const float*)d_in[7];
    const float* b_hh_r = (const float*)d_in[8];
    const float* fc1_w  = (const float*)d_in[9];
    const float* fc1_b  = (const float*)d_in[10];
    const float* fc3_w  = (const float*)d_in[11];
    const float* fc3_b  = (const float*)d_in[12];
    float* out = (float*)d_out;

    const int n = BB * TT;
    init_out_kernel<<<(n + 255) / 256, 256, 0, stream>>>(out, fc1_b, fc3_w, fc3_b, n);

    // 256 workgroups = batch pairs; 6 waves each. 99KB LDS -> exactly one
    // block per CU; 256 blocks = 256 CUs = single round, all work resident.
    lstm_pc_kernel<<<BB / 2, 384, 0, stream>>>(
        x, w_ih_f, w_hh_f, b_ih_f, b_hh_f,
        w_ih_r, w_hh_r, b_ih_r, b_hh_r,
        fc1_w, fc3_w, out);
}

// Round 9
// 418.681 us; speedup vs baseline: 1.5101x; 1.3105x over previous
//
#include <hip/hip_runtime.h>

#define BB 512
#define TT 1024
#define II 50
#define HH 32
#define CH 16            // steps per chunk (barrier cadence; = MFMA M)
#define NCH (TT / CH)    // 64 chunks
#define RSLOT 32         // ring slots = 2 chunks (double buffer)

typedef float v2f __attribute__((ext_vector_type(2)));
typedef float v4f __attribute__((ext_vector_type(4)));
typedef short v8s __attribute__((ext_vector_type(8)));   // 8 bf16 (4 VGPRs)

__device__ __forceinline__ float fast_rcp(float x) { return __builtin_amdgcn_rcpf(x); }
__device__ __forceinline__ float sigm(float x) { return fast_rcp(1.f + __expf(-x)); }
__device__ __forceinline__ float tanh_(float x) {
    return 1.f - 2.f * fast_rcp(1.f + __expf(2.f * x));   // saturates correctly
}
__device__ __forceinline__ short bf16rne(float f) {      // fp32 -> bf16 RNE
    unsigned u = __float_as_uint(f);
    u += 0x7FFF + ((u >> 16) & 1);
    return (short)(u >> 16);
}

// Cross-half (lane ^ 32) sum via v_permlane32_swap: pure-VALU, stays off the
// LDS pipe. The returned pair {r0,r1} contains {own,partner} per lane in
// either hardware convention, so r0+r1 is convention-independent.
#if __has_builtin(__builtin_amdgcn_permlane32_swap)
typedef unsigned v2u __attribute__((ext_vector_type(2)));
__device__ __forceinline__ float xhalf_sum(float p) {
    v2u r = __builtin_amdgcn_permlane32_swap(__float_as_uint(p),
                                             __float_as_uint(p), false, false);
    return __uint_as_float(r.x) + __uint_as_float(r.y);
}
#else
__device__ __forceinline__ float xhalf_sum(float p) {
    return p + __shfl_xor(p, 32, 64);
}
#endif

// d_out is poisoned before every launch: init every element to the combined
// FC bias b_comb = fc3_w @ fc1_b + fc3_b (fc1->fc3 is affine-affine; dropout
// is identity in eval). The scan kernel atomicAdds partial dots on top.
__global__ void init_out_kernel(float* __restrict__ out,
                                const float* __restrict__ fc1_b,
                                const float* __restrict__ fc3_w,
                                const float* __restrict__ fc3_b,
                                int n) {
    int idx = blockIdx.x * blockDim.x + threadIdx.x;
    float b = fc3_b[0];
    #pragma unroll
    for (int k = 0; k < 64; ++k) b += fc3_w[k] * fc1_b[k];
    if (idx < n) out[idx] = b;
}

// One workgroup (384 threads = 6 waves) per PAIR of batches.
// R5 lesson: 1 block/CU required for single-round launch (2 batches/block,
// 256 blocks = 256 CUs). R6 lesson (counters): occupancy fix worked but
// per-step went 620 -> 1055 cy because wave order {c,c,p, c,c,p} put TWO
// consumers on SIMD0 (round-robin wave->SIMD = wave_id%4); barrier couples
// the whole block to that serialized pair. Fix: wave order
//   w0..w3 = consumers (sb = wave>>1, dir = wave&1)  -> one per SIMD
//   w4,w5  = producers (sb = wave-4)                 -> share SIMD0/1
// Producers are ~25% issue duty, acceptable co-tenant for a consumer.
// Consumer wave (one direction): lanes (k=lane&31, kh=lane>>5): unit k,
//   K-half kh. Each lane computes a HALF-dot (K=16 -> 32 pk_fma/wave),
//   combined with one v_permlane32_swap per gate (VALU, not LDS).
//   Activations and c/h state are duplicated across kh halves.
// Producer wave: ih projection for BOTH dirs of its sub-batch via bf16 MFMA
//   (32 MFMA / 16-step chunk), plus deferred-FC flush + atomicAdd.
// Ring layout (per step-slot, 256 floats): col = d*128 + cidx(gate);
//   cidx: i_k->2k, f_k->2k+1, g_k->64+2k, o_k->64+2k+1, so a consumer lane
//   reads two b64s: {zi,zf} at d*128+2k and {zg,zo} at d*128+64+2k.
// Bias is seeded in the kh=0 half-dot accumulator (added exactly once).
// MFMA layouts (guide-verified m89/m118/m120):
//   A (16x32): m=lane&15, k=(lane>>4)*8+j     (8 bf16/lane)
//   B (32x16): n=lane&15, k=(lane>>4)*8+j
//   D (16x16): m=(lane>>4)*4+reg, n=lane&15   (4 fp32/lane)
// CRITICAL (prior-session lesson): empty asm memory clobber at the end of
// each consumer step pins the hst store->load order across unrolled steps.
__global__ void __launch_bounds__(384, 1) lstm_pc_kernel(
    const float* __restrict__ x,
    const float* __restrict__ w_ih_f, const float* __restrict__ w_hh_f,
    const float* __restrict__ b_ih_f, const float* __restrict__ b_hh_f,
    const float* __restrict__ w_ih_r, const float* __restrict__ w_hh_r,
    const float* __restrict__ b_ih_r, const float* __restrict__ b_hh_r,
    const float* __restrict__ fc1_w, const float* __restrict__ fc3_w,
    float* __restrict__ out)
{
    __shared__ float ringF[2][RSLOT * 256];     // 64 KB: per-step gate projections
    __shared__ float hbuf[2][2][HH][65];        // 33.3 KB: deferred FC partials
    __shared__ __align__(16) float hst[2][64];  // 512 B: h(t-1) stage, both dirs

    const int tid  = threadIdx.x;
    const int lane = tid & 63;
    const int wave = tid >> 6;            // 0..5
    // SIMD-collision-aware role decode (R6 lesson):
    //   w0..w3 = consumers: sb = w>>1, d = w&1   (one consumer per SIMD)
    //   w4,w5  = producers: sb = w-4
    const int is_prod = (wave >= 4);
    const int sb   = is_prod ? (wave - 4) : (wave >> 1);
    const int b    = blockIdx.x * 2 + sb;
    float* outb = out + (size_t)b * TT;
    float* ring = ringF[sb];

    if (is_prod) {
        // ================= PRODUCER (MFMA ih projection, both dirs) =========
        const float* xb = x + (size_t)b * TT * II;
        const int nl = lane & 15;         // A: m / B: n / D: n
        const int q  = lane >> 4;         // quad 0..3
        const float* wih[2] = {w_ih_f, w_ih_r};

        // B fragments (persistent): Bf[d][nt][kf], n = nt*16+nl, k = kf*32+q*8+j
        v8s Bf[2][8][2];
        #pragma unroll
        for (int d = 0; d < 2; ++d)
            #pragma unroll
            for (int nt = 0; nt < 8; ++nt) {
                const int n = nt * 16 + nl;
                #pragma unroll
                for (int kf = 0; kf < 2; ++kf)
                    #pragma unroll
                    for (int j = 0; j < 8; ++j) {
                        const int k = kf * 32 + q * 8 + j;
                        Bf[d][nt][kf][j] = (k < II) ? bf16rne(wih[d][n * II + k])
                                                    : (short)0;
                    }
            }

        // gate g -> interleaved ring column
        auto cidx = [](int g) -> int {
            return (g < 32) ? 2 * g
                 : (g < 64) ? 2 * (g - 32) + 1
                 : (g < 96) ? 64 + 2 * (g - 64)
                            : 64 + 2 * (g - 96) + 1;
        };

        // produce chunk c for both dirs: fills ring slots c*CH .. c*CH+15
        auto produce_chunk = [&](int c) {
            #pragma unroll
            for (int d = 0; d < 2; ++d) {
                const int S = c * CH + nl;             // this lane's A-row step
                const int t = d ? (TT - 1 - S) : S;
                const float* xr = xb + (size_t)t * II;
                v8s A0, A1;
                #pragma unroll
                for (int j = 0; j < 8; ++j) A0[j] = bf16rne(xr[q * 8 + j]);
                #pragma unroll
                for (int j = 0; j < 8; ++j) {
                    const int k = 32 + q * 8 + j;
                    A1[j] = (k < II) ? bf16rne(xr[k]) : (short)0;
                }
                #pragma unroll
                for (int nt = 0; nt < 8; ++nt) {
                    v4f acc = {0.f, 0.f, 0.f, 0.f};
                    acc = __builtin_amdgcn_mfma_f32_16x16x32_bf16(A0, Bf[d][nt][0], acc, 0, 0, 0);
                    acc = __builtin_amdgcn_mfma_f32_16x16x32_bf16(A1, Bf[d][nt][1], acc, 0, 0, 0);
                    const int col = d * 128 + cidx(nt * 16 + nl);
                    #pragma unroll
                    for (int r = 0; r < 4; ++r) {
                        const int slot = (c * CH + q * 4 + r) & (RSLOT - 1);
                        ring[slot * 256 + col] = acc[r];
                    }
                }
            }
        };
        // flush chunk m: 16 outputs per dir; lanes 0..31 (d = lane>>4)
        auto flush = [&](int m) {
            if (lane < 32) {
                const int d   = lane >> 4;
                const int idx = lane & 15;
                const int ti  = m * CH + idx;
                const int col = ti & 63;
                float d0 = 0.f, d1 = 0.f, d2 = 0.f, d3 = 0.f;
                #pragma unroll
                for (int k = 0; k < HH; k += 4) {
                    d0 += hbuf[sb][d][k    ][col];
                    d1 += hbuf[sb][d][k + 1][col];
                    d2 += hbuf[sb][d][k + 2][col];
                    d3 += hbuf[sb][d][k + 3][col];
                }
                const int t = d ? (TT - 1 - ti) : ti;
                atomicAdd(&outb[t], (d0 + d1) + (d2 + d3));
            }
        };

        produce_chunk(0);
        __syncthreads();
        for (int n = 0; n < NCH; ++n) {
            if (n + 1 < NCH) produce_chunk(n + 1);
            if (n >= 1) flush(n - 1);
            __syncthreads();
        }
        flush(NCH - 1);
    } else {
        // ================= CONSUMER (fp32 recurrence, dir = wave&1) ========
        const int d  = wave & 1;          // 0 fwd, 1 rev
        const int k  = lane & 31;         // hidden unit
        const int kh = lane >> 5;         // K-half: 0 -> h[0..15], 1 -> h[16..31]
        const float* w_hh = d ? w_hh_r : w_hh_f;
        const float* bi   = d ? b_ih_r : b_ih_f;
        const float* bh   = d ? b_hh_r : b_hh_f;

        // K-packed weight pairs for this lane's K-half of all 4 gate rows:
        // wp[D][j] = {w_hh[D*32+k][16*kh+2j], w_hh[D*32+k][16*kh+2j+1]}
        v2f wp[4][8];
        float bseed[4];
        #pragma unroll
        for (int D = 0; D < 4; ++D) {
            const int row = D * 32 + k;
            #pragma unroll
            for (int j = 0; j < 8; ++j) {
                wp[D][j].x = w_hh[row * HH + 16 * kh + 2 * j];
                wp[D][j].y = w_hh[row * HH + 16 * kh + 2 * j + 1];
            }
            bseed[D] = kh ? 0.f : (bi[row] + bh[row]);   // bias added once
        }

        // fused FC weight for hidden unit j = d*32 + k
        float wc = 0.f;
        {
            const int j = d * HH + k;
            #pragma unroll
            for (int n = 0; n < 64; ++n) wc += fc3_w[n] * fc1_w[n * 64 + j];
        }

        hst[sb][d * 32 + k] = 0.f;        // h(-1)=0 (kh halves write same value)
        float c = 0.f;

        __syncthreads();                  // matches producer's prologue barrier

        for (int n = 0; n < NCH; ++n) {
            const int slot0 = (n & 1) * CH;
            const int col0  = (n & 3) * CH;
            #pragma unroll
            for (int u = 0; u < CH; ++u) {
                // x-projection pairs (off-chain: issued at step top, used late)
                const float* rp = &ring[(slot0 + u) * 256 + d * 128 + 2 * k];
                const v2f xz1 = *(const v2f*)rp;          // {px_i, px_f}
                const v2f xz2 = *(const v2f*)(rp + 64);   // {px_g, px_o}

                // h(t-1) broadcast, this lane's K-half only: 4x b128
                float4 h4[4];
                #pragma unroll
                for (int j = 0; j < 4; ++j)
                    h4[j] = *(const float4*)&hst[sb][d * 32 + kh * 16 + 4 * j];

                v2f acc[4];
                #pragma unroll
                for (int D = 0; D < 4; ++D) acc[D] = (v2f){bseed[D], 0.f};
                #pragma unroll
                for (int j = 0; j < 4; ++j) {
                    v2f p0 = {h4[j].x, h4[j].y};          // adjacent regs, free
                    v2f p1 = {h4[j].z, h4[j].w};
                    #pragma unroll
                    for (int D = 0; D < 4; ++D) {
                        acc[D] = __builtin_elementwise_fma(p0, wp[D][2 * j    ], acc[D]);
                        acc[D] = __builtin_elementwise_fma(p1, wp[D][2 * j + 1], acc[D]);
                    }
                }
                // half-dot -> full dot: horizontal add, then lane^32 combine
                const float zi = xhalf_sum(acc[0].x + acc[0].y) + xz1.x;
                const float zf = xhalf_sum(acc[1].x + acc[1].y) + xz1.y;
                const float zg = xhalf_sum(acc[2].x + acc[2].y) + xz2.x;
                const float zo = xhalf_sum(acc[3].x + acc[3].y) + xz2.y;

                const float gi = sigm(zi);
                const float gf = sigm(zf);
                const float gg = tanh_(zg);
                const float go = sigm(zo);

                c = fmaf(gf, c, gi * gg);
                const float h = go * tanh_(c);

                hst[sb][d * 32 + k] = h;              // kh halves write same value
                hbuf[sb][d][k][col0 + u] = h * wc;    // deferred FC (dup write ok)
                // ordering fence: store(u) may not sink, loads(u+1) may not
                // hoist. Zero instructions emitted.
                asm volatile("" ::: "memory");
            }
            __syncthreads();
        }
    }
}

extern "C" void kernel_launch(void* const* d_in, const int* in_sizes, int n_in,
                              void* d_out, int out_size, void* d_ws, size_t ws_size,
                              hipStream_t stream) {
    const float* x      = (const float*)d_in[0];
    const float* w_ih_f = (const float*)d_in[1];
    const float* w_hh_f = (const float*)d_in[2];
    const float* b_ih_f = (const float*)d_in[3];
    const float* b_hh_f = (const float*)d_in[4];
    const float* w_ih_r = (const float*)d_in[5];
    const float* w_hh_r = (const float*)d_in[6];
    const float* b_ih_r = (const float*)d_in[7];
    const float* b_hh_r = (const float*)d_in[8];
    const float* fc1_w  = (const float*)d_in[9];
    const float* fc1_b  = (const float*)d_in[10];
    const float* fc3_w  = (const float*)d_in[11];
    const float* fc3_b  = (const float*)d_in[12];
    float* out = (float*)d_out;

    const int n = BB * TT;
    init_out_kernel<<<(n + 255) / 256, 256, 0, stream>>>(out, fc1_b, fc3_w, fc3_b, n);

    // 256 workgroups = batch pairs; 6 waves each. 99KB LDS -> exactly one
    // block per CU; 256 blocks = 256 CUs = single round, all work resident.
    lstm_pc_kernel<<<BB / 2, 384, 0, stream>>>(
        x, w_ih_f, w_hh_f, b_ih_f, b_hh_f,
        w_ih_r, w_hh_r, b_ih_r, b_hh_r,
        fc1_w, fc3_w, out);
}